// Round 1
// 138.325 us; speedup vs baseline: 1.0247x; 1.0247x over previous
//
#include <hip/hip_runtime.h>

// Problem constants
#define BB   4
#define NN   30000
#define TT   12
#define EE   240000
#define FT   24        // F_IN * T floats per (b, node)
#define NM   96        // BB * FT
#define CAP  32        // bucket capacity per node (deg ~ Poisson(8); max ~22)
#define OVCAP 2048     // overflow capacity (normally 0 used)
#define FB   ((EE + 255) / 256)      // 938 fill blocks
#define LOG2E 1.44269504088896340736f

// Workspace layout (4-byte elements), total ~4 MB:
//   cnt[NN]          @ 0            (zeroed by memset)
//   ovf_cnt[16]      @ 30000        (zeroed by memset; [0] used)
//   eff[256]  float  @ 30016
//   ovf[2*OVCAP] int @ 30272        ((dst,src) pairs)
//   bucket[NN*CAP]   @ 34368
#define WS_CNT 0
#define WS_OVC 30000
#define WS_EFF 30016
#define WS_OVF 30272
#define WS_BKT 34368

__device__ __forceinline__ float readlane_f(float v, int l) {
    return __int_as_float(__builtin_amdgcn_readlane(__float_as_int(v), l));
}

// ---- one launch: bucket-fill | weight fold --------------------------------
// eff layout: Az0[32] Az1[32] ab[32] Ch0[32] Ch1[32] cb[32] probs[12]
// where A* = -log2e * (Wz folded), C* = 2*log2e * (Wh folded):
//   a = Az0*v0 + Az1*v1 + ab  -> u  = exp2(a) = exp(-zp)
//   c = Ch0*v0 + Ch1*v1 + cb  -> e2 = exp2(c) = exp(2*hp)
__global__ void __launch_bounds__(256)
k_pre(const int* __restrict__ src, const int* __restrict__ dst,
      const float* __restrict__ czw, const float* __restrict__ czb,
      const float* __restrict__ lzw, const float* __restrict__ lzb,
      const float* __restrict__ chw, const float* __restrict__ chb,
      const float* __restrict__ lhw, const float* __restrict__ lhb,
      const float* __restrict__ att,
      int* __restrict__ cnt, int* __restrict__ ovc,
      int* __restrict__ ovf, int* __restrict__ bucket, float* __restrict__ eff) {
    int bid = blockIdx.x, lt = threadIdx.x;
    if (bid < FB) {
        int e = bid * 256 + lt;
        if (e < EE) {
            int d = dst[e], s = src[e];
            int slot = atomicAdd(&cnt[d], 1);
            if (slot < CAP) {
                bucket[d * CAP + slot] = s;
            } else {
                int o = atomicAdd(ovc, 1);
                if (o < OVCAP) { ovf[2 * o] = d; ovf[2 * o + 1] = s; }
            }
        }
        return;
    }
    // last block: weight folding + attention softmax
    int j = lt;
    if (j < 32) {
        float wz0 = 0.f, wz1 = 0.f, bz = 0.f, wh0 = 0.f, wh1 = 0.f, bh = 0.f;
        for (int k = 0; k < 32; ++k) {
            float lz = lzw[k * 32 + j], lh = lhw[k * 32 + j];
            wz0 = fmaf(czw[k],      lz, wz0);
            wz1 = fmaf(czw[32 + k], lz, wz1);
            bz  = fmaf(czb[k],      lz, bz);
            wh0 = fmaf(chw[k],      lh, wh0);
            wh1 = fmaf(chw[32 + k], lh, wh1);
            bh  = fmaf(chb[k],      lh, bh);
        }
        eff[j]        = -LOG2E * wz0;
        eff[32 + j]   = -LOG2E * wz1;
        eff[64 + j]   = -LOG2E * (bz + lzb[j]);
        eff[96 + j]   = 2.0f * LOG2E * wh0;
        eff[128 + j]  = 2.0f * LOG2E * wh1;
        eff[160 + j]  = 2.0f * LOG2E * (bh + lhb[j]);
    } else if (j == 32) {
        float m = -1e30f;
        for (int t = 0; t < TT; ++t) m = fmaxf(m, att[t]);
        float p[TT], s = 0.f;
        for (int t = 0; t < TT; ++t) { p[t] = __expf(att[t] - m); s += p[t]; }
        float inv = 1.0f / s;
        for (int t = 0; t < TT; ++t) eff[192 + t] = p[t] * inv;
    }
}

// ---- fused gather + gates + head: one wave per node -----------------------
// Wave-private LDS regions (sx, lacc) -> no block barriers after the initial
// weight staging; within-wave LDS ordering enforced with s_waitcnt lgkmcnt(0).
__global__ void __launch_bounds__(256)
k_fused(const float* __restrict__ x, const int* __restrict__ cnt,
        const int* __restrict__ ovc, const int* __restrict__ ovf,
        const int* __restrict__ bucket, const float* __restrict__ eff,
        const float* __restrict__ hw, const float* __restrict__ hb,
        float* __restrict__ out) {
    __shared__ __align__(16) float se[204];     // folded weights + probs
    __shared__ __align__(16) float shw[384];    // head_w (32x12)
    __shared__ float shb[12];                   // head_b
    __shared__ __align__(16) float sx[4 * NM];  // per-wave aggregated row, (v0,v1) paired by t
    __shared__ float lacc[4 * 132];             // per-wave relu'd hidden (stride 33)
    const int lt = threadIdx.x, lane = lt & 63, w = lt >> 6;
    const int n = blockIdx.x * 4 + w;  // 7500 blocks * 4 waves = 30000 nodes

    // vectorized weight staging: 384+204 floats as float4 + 12 scalars
    if (lt < 96)       ((float4*)shw)[lt]      = ((const float4*)hw)[lt];
    else if (lt < 147) ((float4*)se)[lt - 96]  = ((const float4*)eff)[lt - 96];
    else if (lt < 159) shb[lt - 147]           = hb[lt - 147];
    __syncthreads();   // the only block-wide barrier

    const bool act = (lane < 48);
    const int b = lane / 12, f2 = lane - 12 * b;       // valid when lane<48
    const float2* xb = (const float2*)x;
    const int lane_off = b * (NN * 12) + f2;           // float2 units

    // Speculative front-end: bucket row and cnt[n] issued together (independent);
    // cnt[spec-src] issued as soon as the bucket row lands (clamped -> safe on
    // stale/poison slots; cnt is 120 KB = L2-resident, mispredicated reads are cheap).
    int bval = 0;
    if (lane < CAP) bval = bucket[n * CAP + lane];
    const int cn  = cnt[n];
    const int nov0 = *ovc;                              // hoisted, overlaps
    const int bv2 = ((unsigned)bval < (unsigned)NN) ? bval : n;
    int cv = 0;
    if (lane < CAP) cv = cnt[bv2];

    const int deg = __builtin_amdgcn_readfirstlane(cn);
    const int m = (deg < CAP) ? deg : CAP;
    // lane m = self loop (sv=n, wv=dn); lanes (m, mm8) padded with wv=0.
    const int sv = (lane < m) ? bv2 : n;
    const int cc = (lane < m) ? cv : deg;               // lanes >= m see deg -> dn
    const float wv = (lane <= m) ? rsqrtf((float)(cc + 1)) : 0.f;

    float2 acc = {0.f, 0.f};
    const int mm8 = (m + 8) & ~7;      // (m+1) rounded up to multiple of 8
    for (int k = 0; k < mm8; k += 8) {
        int s0 = __builtin_amdgcn_readlane(sv, k);
        int s1 = __builtin_amdgcn_readlane(sv, k + 1);
        int s2 = __builtin_amdgcn_readlane(sv, k + 2);
        int s3 = __builtin_amdgcn_readlane(sv, k + 3);
        int s4 = __builtin_amdgcn_readlane(sv, k + 4);
        int s5 = __builtin_amdgcn_readlane(sv, k + 5);
        int s6 = __builtin_amdgcn_readlane(sv, k + 6);
        int s7 = __builtin_amdgcn_readlane(sv, k + 7);
        if (act) {
            // all 8 loads independent -> issued back-to-back (1 round-trip)
            float2 v0 = xb[lane_off + s0 * 12];
            float2 v1 = xb[lane_off + s1 * 12];
            float2 v2 = xb[lane_off + s2 * 12];
            float2 v3 = xb[lane_off + s3 * 12];
            float2 v4 = xb[lane_off + s4 * 12];
            float2 v5 = xb[lane_off + s5 * 12];
            float2 v6 = xb[lane_off + s6 * 12];
            float2 v7 = xb[lane_off + s7 * 12];
            float w0 = readlane_f(wv, k),     w1 = readlane_f(wv, k + 1);
            float w2 = readlane_f(wv, k + 2), w3 = readlane_f(wv, k + 3);
            float w4 = readlane_f(wv, k + 4), w5 = readlane_f(wv, k + 5);
            float w6 = readlane_f(wv, k + 6), w7 = readlane_f(wv, k + 7);
            acc.x = fmaf(w0, v0.x, acc.x); acc.y = fmaf(w0, v0.y, acc.y);
            acc.x = fmaf(w1, v1.x, acc.x); acc.y = fmaf(w1, v1.y, acc.y);
            acc.x = fmaf(w2, v2.x, acc.x); acc.y = fmaf(w2, v2.y, acc.y);
            acc.x = fmaf(w3, v3.x, acc.x); acc.y = fmaf(w3, v3.y, acc.y);
            acc.x = fmaf(w4, v4.x, acc.x); acc.y = fmaf(w4, v4.y, acc.y);
            acc.x = fmaf(w5, v5.x, acc.x); acc.y = fmaf(w5, v5.y, acc.y);
            acc.x = fmaf(w6, v6.x, acc.x); acc.y = fmaf(w6, v6.y, acc.y);
            acc.x = fmaf(w7, v7.x, acc.x); acc.y = fmaf(w7, v7.y, acc.y);
        }
    }

    // overflow edges (normally zero)
    int nov = __builtin_amdgcn_readfirstlane(nov0);
    if (nov > 0) {
        if (nov > OVCAP) nov = OVCAP;
        for (int i = 0; i < nov; ++i) {
            int d = ovf[2 * i];
            if (d == n) {
                int s = ovf[2 * i + 1];
                float ws_ = rsqrtf((float)(cnt[s] + 1));
                if (act) {
                    float2 v = xb[lane_off + s * 12];
                    acc.x = fmaf(ws_, v.x, acc.x);
                    acc.y = fmaf(ws_, v.y, acc.y);
                }
            }
        }
    }

    const float dn = readlane_f(wv, m);   // rsqrt(deg_n + 1)
    if (act) {
        // paired layout: float idx 2t = v0[t], 2t+1 = v1[t]
        // lane f2<6 holds (f=0, t=2f2, 2f2+1) -> idx 4f2, 4f2+2
        // lane f2>=6 holds (f=1, t=2(f2-6), ..) -> idx 4(f2-6)+1, +3
        float* sxw = sx + w * NM + b * FT;
        const int g = (f2 < 6) ? (4 * f2) : (4 * (f2 - 6) + 1);
        sxw[g]     = dn * acc.x;
        sxw[g + 2] = dn * acc.y;
    }

    // ---- gates: lane handles (b0, j) and (b0+2, j); merged single-rcp ----
    const int j = lane & 31, b0_ = lane >> 5;
    const float az0 = se[j],      az1 = se[32 + j],  ab = se[64 + j];
    const float ch0 = se[96 + j], ch1 = se[128 + j], cb = se[160 + j];
    float pt[TT];
#pragma unroll
    for (int t = 0; t < TT; ++t) pt[t] = se[192 + t];
    // within-wave LDS write->read ordering (replaces __syncthreads)
    asm volatile("s_waitcnt lgkmcnt(0)" ::: "memory");
#pragma unroll
    for (int bi = 0; bi < 2; ++bi) {
        const int bb = b0_ + 2 * bi;
        const float2* srow2 = (const float2*)(sx + w * NM + bb * FT);
        float a = 0.f;
#pragma unroll
        for (int t = 0; t < TT; ++t) {
            float2 v = srow2[t];                             // (v0[t], v1[t])
            float ae = fmaf(v.y, az1, fmaf(v.x, az0, ab));   // -zp*log2e
            float ce = fmaf(v.y, ch1, fmaf(v.x, ch0, cb));   // 2*hp*log2e
            ae = fminf(fmaxf(ae, -60.f), 60.f);
            ce = fminf(fmaxf(ce, -60.f), 60.f);
            float u  = __builtin_amdgcn_exp2f(ae);           // exp(-zp)
            float e2 = __builtin_amdgcn_exp2f(ce);           // exp(2*hp)
            float t1  = 1.0f + u;
            float den = fmaf(e2, t1, t1);                    // (1+u)(1+e2)
            float num = fmaf(u, e2, -u);                     // u(e2-1)
            float r   = __builtin_amdgcn_rcpf(den);
            a = fmaf(pt[t] * num, r, a);                     // += p*(1-z)*tanh
        }
        lacc[w * 132 + bb * 33 + j] = fmaxf(a, 0.f);
    }
    asm volatile("s_waitcnt lgkmcnt(0)" ::: "memory");

    // ---- head: lanes 0..47 produce (b, k) ----
    if (lane < 48) {
        int bb = lane / 12, kk = lane - 12 * bb;
        float r = shb[kk];
        const float* la = lacc + w * 132 + bb * 33;
#pragma unroll
        for (int jj = 0; jj < 32; ++jj)
            r = fmaf(la[jj], shw[jj * 12 + kk], r);
        out[((long long)bb * NN + n) * 12 + kk] = r;
    }
}

extern "C" void kernel_launch(void* const* d_in, const int* in_sizes, int n_in,
                              void* d_out, int out_size, void* d_ws, size_t ws_size,
                              hipStream_t stream) {
    const float* x   = (const float*)d_in[0];
    const int*   ei  = (const int*)d_in[1];     // (2,E): [0,E)=src, [E,2E)=dst
    const float* att = (const float*)d_in[2];
    const float* czw = (const float*)d_in[3];
    const float* czb = (const float*)d_in[4];
    const float* lzw = (const float*)d_in[5];
    const float* lzb = (const float*)d_in[6];
    // d_in[7..10] (conv_r / lin_r) dead: H0 == 0 so H0*R == 0
    const float* chw = (const float*)d_in[11];
    const float* chb = (const float*)d_in[12];
    const float* lhw = (const float*)d_in[13];
    const float* lhb = (const float*)d_in[14];
    const float* hw  = (const float*)d_in[15];
    const float* hb  = (const float*)d_in[16];
    float* out = (float*)d_out;

    float* ws = (float*)d_ws;
    int*   cnt = (int*)(ws + WS_CNT);
    int*   ovc = (int*)(ws + WS_OVC);
    float* eff = ws + WS_EFF;
    int*   ovf = (int*)(ws + WS_OVF);
    int*   bkt = (int*)(ws + WS_BKT);

    const int* src = ei;
    const int* dst = ei + EE;

    hipMemsetAsync(cnt, 0, WS_EFF * 4, stream);   // zero cnt + ovf_cnt
    k_pre<<<FB + 1, 256, 0, stream>>>(src, dst, czw, czb, lzw, lzb,
                                      chw, chb, lhw, lhb, att,
                                      cnt, ovc, ovf, bkt, eff);
    k_fused<<<NN / 4, 256, 0, stream>>>(x, cnt, ovc, ovf, bkt, eff, hw, hb, out);
}

// Round 2
// 137.730 us; speedup vs baseline: 1.0291x; 1.0043x over previous
//
#include <hip/hip_runtime.h>

// Problem constants
#define BB   4
#define NN   30000
#define TT   12
#define EE   240000
#define FT   24        // F_IN * T floats per (b, node)
#define NM   96        // BB * FT
#define CAP  32        // bucket capacity per node (deg ~ Poisson(8); max ~22)
#define OVCAP 2048     // overflow capacity (normally 0 used)
#define FB   ((EE + 255) / 256)      // 938 fill blocks
#define LOG2E 1.44269504088896340736f

// Workspace layout (4-byte elements), total ~4 MB:
//   cnt[NN]          @ 0            (zeroed by memset)
//   ovf_cnt[16]      @ 30000        (zeroed by memset; [0] used)
//   eff[256]  float  @ 30016
//   ovf[2*OVCAP] int @ 30272        ((dst,src) pairs)
//   bucket[NN*CAP]   @ 34368
#define WS_CNT 0
#define WS_OVC 30000
#define WS_EFF 30016
#define WS_OVF 30272
#define WS_BKT 34368

__device__ __forceinline__ float readlane_f(float v, int l) {
    return __int_as_float(__builtin_amdgcn_readlane(__float_as_int(v), l));
}

// ---- one launch: bucket-fill | weight fold --------------------------------
// eff layout: Az0[32] Az1[32] ab[32] Ch0[32] Ch1[32] cb[32] probs[12]
// where A* = -log2e * (Wz folded), C* = 2*log2e * (Wh folded):
//   a = Az0*v0 + Az1*v1 + ab  -> u  = exp2(a) = exp(-zp)
//   c = Ch0*v0 + Ch1*v1 + cb  -> e2 = exp2(c) = exp(2*hp)
__global__ void __launch_bounds__(256)
k_pre(const int* __restrict__ src, const int* __restrict__ dst,
      const float* __restrict__ czw, const float* __restrict__ czb,
      const float* __restrict__ lzw, const float* __restrict__ lzb,
      const float* __restrict__ chw, const float* __restrict__ chb,
      const float* __restrict__ lhw, const float* __restrict__ lhb,
      const float* __restrict__ att,
      int* __restrict__ cnt, int* __restrict__ ovc,
      int* __restrict__ ovf, int* __restrict__ bucket, float* __restrict__ eff) {
    int bid = blockIdx.x, lt = threadIdx.x;
    if (bid < FB) {
        int e = bid * 256 + lt;
        if (e < EE) {
            int d = dst[e], s = src[e];
            int slot = atomicAdd(&cnt[d], 1);
            if (slot < CAP) {
                bucket[d * CAP + slot] = s;
            } else {
                int o = atomicAdd(ovc, 1);
                if (o < OVCAP) { ovf[2 * o] = d; ovf[2 * o + 1] = s; }
            }
        }
        return;
    }
    // last block: weight folding + attention softmax
    int j = lt;
    if (j < 32) {
        float wz0 = 0.f, wz1 = 0.f, bz = 0.f, wh0 = 0.f, wh1 = 0.f, bh = 0.f;
        for (int k = 0; k < 32; ++k) {
            float lz = lzw[k * 32 + j], lh = lhw[k * 32 + j];
            wz0 = fmaf(czw[k],      lz, wz0);
            wz1 = fmaf(czw[32 + k], lz, wz1);
            bz  = fmaf(czb[k],      lz, bz);
            wh0 = fmaf(chw[k],      lh, wh0);
            wh1 = fmaf(chw[32 + k], lh, wh1);
            bh  = fmaf(chb[k],      lh, bh);
        }
        eff[j]        = -LOG2E * wz0;
        eff[32 + j]   = -LOG2E * wz1;
        eff[64 + j]   = -LOG2E * (bz + lzb[j]);
        eff[96 + j]   = 2.0f * LOG2E * wh0;
        eff[128 + j]  = 2.0f * LOG2E * wh1;
        eff[160 + j]  = 2.0f * LOG2E * (bh + lhb[j]);
    } else if (j == 32) {
        float m = -1e30f;
        for (int t = 0; t < TT; ++t) m = fmaxf(m, att[t]);
        float p[TT], s = 0.f;
        for (int t = 0; t < TT; ++t) { p[t] = __expf(att[t] - m); s += p[t]; }
        float inv = 1.0f / s;
        for (int t = 0; t < TT; ++t) eff[192 + t] = p[t] * inv;
    }
}

// ---- fused gather + gates + head: one wave per node -----------------------
// ZERO block barriers. Gate weights are read straight into registers from
// global (coalesced per lane). Head weights are staged into LDS redundantly
// by every wave (benign same-value race) so each wave only relies on its own
// lgkmcnt ordering. sx/lacc are wave-private. Waves never wait on each other.
__global__ void __launch_bounds__(256)
k_fused(const float* __restrict__ x, const int* __restrict__ cnt,
        const int* __restrict__ ovc, const int* __restrict__ ovf,
        const int* __restrict__ bucket, const float* __restrict__ eff,
        const float* __restrict__ hw, const float* __restrict__ hb,
        float* __restrict__ out) {
    __shared__ __align__(16) float shw[384];    // head_w (32x12), wave-redundant staged
    __shared__ float shb[12];                   // head_b
    __shared__ __align__(16) float sx[4 * NM];  // per-wave aggregated row, (v0,v1) paired by t
    __shared__ float lacc[4 * 132];             // per-wave relu'd hidden (stride 33)
    const int lt = threadIdx.x, lane = lt & 63, w = lt >> 6;
    const int n = blockIdx.x * 4 + w;  // 7500 blocks * 4 waves = 30000 nodes

    // ---- front-end loads first: addresses depend only on blockIdx --------
    int bval = 0;
    if (lane < CAP) bval = bucket[n * CAP + lane];
    const int cn  = cnt[n];
    const int nov0 = *ovc;

    // ---- gate weights straight to registers (coalesced: j = lane&31) -----
    const int j = lane & 31;
    const float az0 = eff[j],      az1 = eff[32 + j],  ab = eff[64 + j];
    const float ch0 = eff[96 + j], ch1 = eff[128 + j], cb = eff[160 + j];
    float pt[TT];
#pragma unroll
    for (int t = 0; t < TT; ++t) pt[t] = eff[192 + t];   // broadcast loads

    // ---- head weights: wave-redundant LDS staging (no barrier) -----------
    ((float4*)shw)[lane] = ((const float4*)hw)[lane];              // 64 of 96
    if (lane < 32) ((float4*)shw)[64 + lane] = ((const float4*)hw)[64 + lane];
    if (lane < 12) shb[lane] = hb[lane];

    const bool act = (lane < 48);
    const int b = lane / 12, f2 = lane - 12 * b;       // valid when lane<48
    const float2* xb = (const float2*)x;
    const int lane_off = b * (NN * 12) + f2;           // float2 units

    // Speculative: cnt[spec-src] issued as soon as the bucket row lands
    // (clamped -> safe on stale/poison slots; cnt is L2-resident).
    const int bv2 = ((unsigned)bval < (unsigned)NN) ? bval : n;
    int cv = 0;
    if (lane < CAP) cv = cnt[bv2];

    const int deg = __builtin_amdgcn_readfirstlane(cn);
    const int m = (deg < CAP) ? deg : CAP;
    // lane m = self loop (sv=n, wv=dn); lanes (m, mm8) padded with wv=0.
    const int sv = (lane < m) ? bv2 : n;
    const int cc = (lane < m) ? cv : deg;               // lanes >= m see deg -> dn
    const float wv = (lane <= m) ? rsqrtf((float)(cc + 1)) : 0.f;

    float2 acc = {0.f, 0.f};
    const int mm8 = (m + 8) & ~7;      // (m+1) rounded up to multiple of 8
    for (int k = 0; k < mm8; k += 8) {
        int s0 = __builtin_amdgcn_readlane(sv, k);
        int s1 = __builtin_amdgcn_readlane(sv, k + 1);
        int s2 = __builtin_amdgcn_readlane(sv, k + 2);
        int s3 = __builtin_amdgcn_readlane(sv, k + 3);
        int s4 = __builtin_amdgcn_readlane(sv, k + 4);
        int s5 = __builtin_amdgcn_readlane(sv, k + 5);
        int s6 = __builtin_amdgcn_readlane(sv, k + 6);
        int s7 = __builtin_amdgcn_readlane(sv, k + 7);
        if (act) {
            // all 8 loads independent -> issued back-to-back (1 round-trip)
            float2 v0 = xb[lane_off + s0 * 12];
            float2 v1 = xb[lane_off + s1 * 12];
            float2 v2 = xb[lane_off + s2 * 12];
            float2 v3 = xb[lane_off + s3 * 12];
            float2 v4 = xb[lane_off + s4 * 12];
            float2 v5 = xb[lane_off + s5 * 12];
            float2 v6 = xb[lane_off + s6 * 12];
            float2 v7 = xb[lane_off + s7 * 12];
            float w0 = readlane_f(wv, k),     w1 = readlane_f(wv, k + 1);
            float w2 = readlane_f(wv, k + 2), w3 = readlane_f(wv, k + 3);
            float w4 = readlane_f(wv, k + 4), w5 = readlane_f(wv, k + 5);
            float w6 = readlane_f(wv, k + 6), w7 = readlane_f(wv, k + 7);
            acc.x = fmaf(w0, v0.x, acc.x); acc.y = fmaf(w0, v0.y, acc.y);
            acc.x = fmaf(w1, v1.x, acc.x); acc.y = fmaf(w1, v1.y, acc.y);
            acc.x = fmaf(w2, v2.x, acc.x); acc.y = fmaf(w2, v2.y, acc.y);
            acc.x = fmaf(w3, v3.x, acc.x); acc.y = fmaf(w3, v3.y, acc.y);
            acc.x = fmaf(w4, v4.x, acc.x); acc.y = fmaf(w4, v4.y, acc.y);
            acc.x = fmaf(w5, v5.x, acc.x); acc.y = fmaf(w5, v5.y, acc.y);
            acc.x = fmaf(w6, v6.x, acc.x); acc.y = fmaf(w6, v6.y, acc.y);
            acc.x = fmaf(w7, v7.x, acc.x); acc.y = fmaf(w7, v7.y, acc.y);
        }
    }

    // overflow edges (normally zero)
    int nov = __builtin_amdgcn_readfirstlane(nov0);
    if (nov > 0) {
        if (nov > OVCAP) nov = OVCAP;
        for (int i = 0; i < nov; ++i) {
            int d = ovf[2 * i];
            if (d == n) {
                int s = ovf[2 * i + 1];
                float ws_ = rsqrtf((float)(cnt[s] + 1));
                if (act) {
                    float2 v = xb[lane_off + s * 12];
                    acc.x = fmaf(ws_, v.x, acc.x);
                    acc.y = fmaf(ws_, v.y, acc.y);
                }
            }
        }
    }

    const float dn = readlane_f(wv, m);   // rsqrt(deg_n + 1)
    if (act) {
        // paired layout: float idx 2t = v0[t], 2t+1 = v1[t]
        // lane f2<6 holds (f=0, t=2f2, 2f2+1) -> idx 4f2, 4f2+2
        // lane f2>=6 holds (f=1, t=2(f2-6), ..) -> idx 4(f2-6)+1, +3
        float* sxw = sx + w * NM + b * FT;
        const int g = (f2 < 6) ? (4 * f2) : (4 * (f2 - 6) + 1);
        sxw[g]     = dn * acc.x;
        sxw[g + 2] = dn * acc.y;
    }

    // within-wave LDS write->read ordering (replaces __syncthreads)
    asm volatile("s_waitcnt lgkmcnt(0)" ::: "memory");

    // ---- gates: lane handles (b0, j) and (b0+2, j); merged single-rcp ----
    const int b0_ = lane >> 5;
#pragma unroll
    for (int bi = 0; bi < 2; ++bi) {
        const int bb = b0_ + 2 * bi;
        const float2* srow2 = (const float2*)(sx + w * NM + bb * FT);
        float a = 0.f;
#pragma unroll
        for (int t = 0; t < TT; ++t) {
            float2 v = srow2[t];                             // (v0[t], v1[t])
            float ae = fmaf(v.y, az1, fmaf(v.x, az0, ab));   // -zp*log2e
            float ce = fmaf(v.y, ch1, fmaf(v.x, ch0, cb));   // 2*hp*log2e
            ae = fminf(fmaxf(ae, -60.f), 60.f);
            ce = fminf(fmaxf(ce, -60.f), 60.f);
            float u  = __builtin_amdgcn_exp2f(ae);           // exp(-zp)
            float e2 = __builtin_amdgcn_exp2f(ce);           // exp(2*hp)
            float t1  = 1.0f + u;
            float den = fmaf(e2, t1, t1);                    // (1+u)(1+e2)
            float num = fmaf(u, e2, -u);                     // u(e2-1)
            float r   = __builtin_amdgcn_rcpf(den);
            a = fmaf(pt[t] * num, r, a);                     // += p*(1-z)*tanh
        }
        lacc[w * 132 + bb * 33 + j] = fmaxf(a, 0.f);
    }
    asm volatile("s_waitcnt lgkmcnt(0)" ::: "memory");

    // ---- head: lanes 0..47 produce (b, k) ----
    if (lane < 48) {
        int bb = lane / 12, kk = lane - 12 * bb;
        float r = shb[kk];
        const float* la = lacc + w * 132 + bb * 33;
#pragma unroll
        for (int jj = 0; jj < 32; ++jj)
            r = fmaf(la[jj], shw[jj * 12 + kk], r);
        out[((long long)bb * NN + n) * 12 + kk] = r;
    }
}

extern "C" void kernel_launch(void* const* d_in, const int* in_sizes, int n_in,
                              void* d_out, int out_size, void* d_ws, size_t ws_size,
                              hipStream_t stream) {
    const float* x   = (const float*)d_in[0];
    const int*   ei  = (const int*)d_in[1];     // (2,E): [0,E)=src, [E,2E)=dst
    const float* att = (const float*)d_in[2];
    const float* czw = (const float*)d_in[3];
    const float* czb = (const float*)d_in[4];
    const float* lzw = (const float*)d_in[5];
    const float* lzb = (const float*)d_in[6];
    // d_in[7..10] (conv_r / lin_r) dead: H0 == 0 so H0*R == 0
    const float* chw = (const float*)d_in[11];
    const float* chb = (const float*)d_in[12];
    const float* lhw = (const float*)d_in[13];
    const float* lhb = (const float*)d_in[14];
    const float* hw  = (const float*)d_in[15];
    const float* hb  = (const float*)d_in[16];
    float* out = (float*)d_out;

    float* ws = (float*)d_ws;
    int*   cnt = (int*)(ws + WS_CNT);
    int*   ovc = (int*)(ws + WS_OVC);
    float* eff = ws + WS_EFF;
    int*   ovf = (int*)(ws + WS_OVF);
    int*   bkt = (int*)(ws + WS_BKT);

    const int* src = ei;
    const int* dst = ei + EE;

    hipMemsetAsync(cnt, 0, WS_EFF * 4, stream);   // zero cnt + ovf_cnt
    k_pre<<<FB + 1, 256, 0, stream>>>(src, dst, czw, czb, lzw, lzb,
                                      chw, chb, lhw, lhb, att,
                                      cnt, ovc, ovf, bkt, eff);
    k_fused<<<NN / 4, 256, 0, stream>>>(x, cnt, ovc, ovf, bkt, eff, hw, hb, out);
}